// Round 2
// baseline (1069.282 us; speedup 1.0000x reference)
//
#include <hip/hip_runtime.h>
#include <math.h>

// Problem constants
#define T_LEN  256
#define BATCH  32
#define EMBD   256
#define HHD    256           // per-direction hidden
#define NTAGS  12
#define NEGV   (-10000.0f)

// ---------------------------------------------------------------------------
// Kernel 1: zx = gather(embed)[m,:] @ [W_ih_f | W_ih_b]^T + bias
// M = 8192 rows (m = t*32 + b), N = 2048, K = 256. 128x128x16 tile.
// ---------------------------------------------------------------------------
__global__ __launch_bounds__(256) void gemm_zx(
    const int* __restrict__ sentence, const float* __restrict__ embed,
    const float* __restrict__ Wf,  const float* __restrict__ Wb,
    const float* __restrict__ bf,  const float* __restrict__ bb,
    float* __restrict__ zx)
{
    __shared__ float As[16][132];
    __shared__ float Bs[16][132];

    const int tid = threadIdx.x;
    const int tx = tid & 15, ty = tid >> 4;
    const int Mbase = (int)(blockIdx.x >> 4) * 128;
    const int Nbase = (int)(blockIdx.x & 15) * 128;

    const float* Wsrc = (Nbase < 1024) ? Wf : Wb;
    const float* bsrc = (Nbase < 1024) ? bf : bb;
    const int nOff = (Nbase < 1024) ? Nbase : (Nbase - 1024);

    const int m0 = tid >> 2;
    const int m1 = m0 + 64;
    const int kq = (tid & 3) * 4;
    const int mg0 = Mbase + m0, mg1 = Mbase + m1;
    const int tok0 = sentence[(mg0 & 31) * T_LEN + (mg0 >> 5)];
    const int tok1 = sentence[(mg1 & 31) * T_LEN + (mg1 >> 5)];
    const float* arow0 = embed + (long long)tok0 * EMBD;
    const float* arow1 = embed + (long long)tok1 * EMBD;
    const float* brow0 = Wsrc + (long long)(nOff + m0) * EMBD;
    const float* brow1 = Wsrc + (long long)(nOff + m1) * EMBD;

    float acc[8][8];
#pragma unroll
    for (int i = 0; i < 8; ++i)
#pragma unroll
        for (int j = 0; j < 8; ++j) acc[i][j] = 0.0f;

    for (int k0 = 0; k0 < EMBD; k0 += 16) {
        float4 av0 = *(const float4*)(arow0 + k0 + kq);
        float4 av1 = *(const float4*)(arow1 + k0 + kq);
        float4 bv0 = *(const float4*)(brow0 + k0 + kq);
        float4 bv1 = *(const float4*)(brow1 + k0 + kq);
        __syncthreads();
        As[kq+0][m0] = av0.x; As[kq+1][m0] = av0.y; As[kq+2][m0] = av0.z; As[kq+3][m0] = av0.w;
        As[kq+0][m1] = av1.x; As[kq+1][m1] = av1.y; As[kq+2][m1] = av1.z; As[kq+3][m1] = av1.w;
        Bs[kq+0][m0] = bv0.x; Bs[kq+1][m0] = bv0.y; Bs[kq+2][m0] = bv0.z; Bs[kq+3][m0] = bv0.w;
        Bs[kq+0][m1] = bv1.x; Bs[kq+1][m1] = bv1.y; Bs[kq+2][m1] = bv1.z; Bs[kq+3][m1] = bv1.w;
        __syncthreads();
#pragma unroll
        for (int kt = 0; kt < 16; ++kt) {
            float am[8], bn[8];
            *(float4*)&am[0] = *(const float4*)&As[kt][ty * 4];
            *(float4*)&am[4] = *(const float4*)&As[kt][64 + ty * 4];
            *(float4*)&bn[0] = *(const float4*)&Bs[kt][tx * 4];
            *(float4*)&bn[4] = *(const float4*)&Bs[kt][64 + tx * 4];
#pragma unroll
            for (int i = 0; i < 8; ++i)
#pragma unroll
                for (int j = 0; j < 8; ++j) acc[i][j] += am[i] * bn[j];
        }
    }

    float4 bias0 = *(const float4*)(bsrc + nOff + tx * 4);
    float4 bias1 = *(const float4*)(bsrc + nOff + 64 + tx * 4);
    const float bnv[8] = {bias0.x, bias0.y, bias0.z, bias0.w,
                          bias1.x, bias1.y, bias1.z, bias1.w};
#pragma unroll
    for (int i = 0; i < 8; ++i) {
        const int mg = Mbase + ty * 4 + (i & 3) + ((i >= 4) ? 64 : 0);
        float4 o0 = make_float4(acc[i][0] + bnv[0], acc[i][1] + bnv[1],
                                acc[i][2] + bnv[2], acc[i][3] + bnv[3]);
        float4 o1 = make_float4(acc[i][4] + bnv[4], acc[i][5] + bnv[5],
                                acc[i][6] + bnv[6], acc[i][7] + bnv[7]);
        *(float4*)(zx + (long long)mg * 2048 + Nbase + tx * 4) = o0;
        *(float4*)(zx + (long long)mg * 2048 + Nbase + 64 + tx * 4) = o1;
    }
}

// ---------------------------------------------------------------------------
// Kernel 1b: pack W_hh into per-(slice,thread) contiguous 512 B chunks:
// offset = (((d*4+q)*2 + half)*256 + j)*128 + k2
//   j = gate-row within WG (g = j>>6, e = q*64 + (j&63)), k = half*128+k2.
// lstm_team WG with slice sl = d*4+q, thread tid reads chunk at tid*128.
// ---------------------------------------------------------------------------
__global__ __launch_bounds__(256) void pack_whh(
    const float* __restrict__ Whf, const float* __restrict__ Whb,
    float* __restrict__ pack)
{
    const int gid = blockIdx.x * 256 + threadIdx.x;   // 0..524287
    const int k2   = gid & 127;
    const int j    = (gid >> 7) & 255;
    const int half = (gid >> 15) & 1;
    const int q    = (gid >> 16) & 3;
    const int d    = (gid >> 18) & 1;
    const float* W = d ? Whb : Whf;
    const int g = j >> 6;
    const int e = q * 64 + (j & 63);
    pack[gid] = W[(g * 256 + e) * 256 + half * 128 + k2];
}

// ---------------------------------------------------------------------------
// Kernel 2: REGISTER-RESIDENT team LSTM.
// 256 WGs x 512 threads.
// R2 (this round): HANG-PROOF dual-channel h-exchange.
//   - blockIdx remap: bx = (d*4 + b[4:3])<<5 | q<<3 | b[2:0].  The 4
//     q-partners of a (b,d) group differ ONLY in bits 4:3, so they share
//     bx%8 (round-robin XCD heuristic) AND bx/32 (chunked heuristic) ->
//     co-located on one XCD under either dispatch policy. Placement is
//     still UNDEFINED (G16) -> never relied on for correctness:
//   - Producer stores every h-slot TWICE: plain volatile store to hxF
//     (lands in producer-XCD L2; visible to same-XCD sc0 loads ~300cy)
//     and the R0-proven agent-scope atomic store to hxS. Both drain at
//     the same barrier -> producer cost unchanged vs the 895us baseline.
//   - Consumer: BOUNDED (1024-iter) sc0 poll on hxF; tag match -> use it.
//     Timeout -> latch fastOK=0 forever, fall into the baseline unbounded
//     agent-scope poll on hxS. Every spin terminates via the proven
//     channel; a wrong placement costs perf (one ~100us latch window),
//     never correctness, never a hang.
// Exchange payloads unchanged: tagged u64 {step,f32} ping-pong, one slot
// per polling thread, single-writer slots. c state in wave-0 registers.
// W pinned via empty inline-asm "+v" clobbers (R5 lesson: the backend
// rematerializes loop-invariant global loads otherwise).
// ---------------------------------------------------------------------------
__global__ __launch_bounds__(512, 2) void lstm_team(
    const float* __restrict__ zx, const float* __restrict__ pack,
    const float* __restrict__ h0, const float* __restrict__ c0,
    unsigned long long* __restrict__ hxF,   // fast: [2 par][2 d][32 b][256 e]
    unsigned long long* __restrict__ hxS,   // slow: same layout
    float* __restrict__ lstm_out)
{
    __shared__ float hS0[256];
    __shared__ float hS1[256];
    __shared__ float pS[512];

    const int tid = threadIdx.x;
    const int bx  = (int)blockIdx.x;
    const int b  = ((bx >> 5) & 3) * 8 + (bx & 7);
    const int q  = (bx >> 3) & 3;
    const int d  = (bx >> 7) & 1;
    const int sl = d * 4 + q;

    // --- W half-row into registers (one-time, coalesced) ---
    float4 wreg[32];
    {
        const float4* wrow = (const float4*)(pack + ((long long)sl << 16)
                                             + tid * 128);
#pragma unroll
        for (int c = 0; c < 32; ++c) wreg[c] = wrow[c];
    }
    // Forbid rematerialization: values become asm outputs, not loads.
#pragma unroll
    for (int c = 0; c < 32; ++c) {
        asm volatile("" : "+v"(wreg[c].x), "+v"(wreg[c].y),
                          "+v"(wreg[c].z), "+v"(wreg[c].w));
    }

    const int half = tid >> 8;            // k-half this thread dots
    const long long hxbase = (long long)(d * 32 + b) * 256;
    const long long zbase = (long long)d * 1024 + q * 64 + (tid & 63);
    float creg = (tid < 64) ? c0[(d * 32 + b) * 256 + q * 64 + tid] : 0.0f;
    int fastOK = 1;

    if (tid < 256) hS0[tid] = h0[(d * 32 + b) * 256 + tid];
    __syncthreads();

    for (int s = 0; s < T_LEN; ++s) {
        const int t = d ? (T_LEN - 1 - s) : s;

        // zx prefetch for gate wave (issued before dot; vmcnt hides latency)
        float zv0 = 0.f, zv1 = 0.f, zv2 = 0.f, zv3 = 0.f;
        if (tid < 64) {
            const float* zr = zx + (long long)(t * 32 + b) * 2048 + zbase;
            zv0 = zr[0]; zv1 = zr[256]; zv2 = zr[512]; zv3 = zr[768];
        }

        const float* h  = (s & 1) ? hS1 : hS0;
        float*       hN = (s & 1) ? hS0 : hS1;
        const float* hh = h + half * 128;   // wave-uniform -> LDS broadcast

        // --- half-dot from registers ---
        float a = 0.0f;
#pragma unroll
        for (int c = 0; c < 32; ++c) {
            const float4 hv = *(const float4*)(hh + c * 4);
            a += wreg[c].x * hv.x + wreg[c].y * hv.y
               + wreg[c].z * hv.z + wreg[c].w * hv.w;
        }
        pS[tid] = a;
        __syncthreads();

        const int parN = (s & 1) ^ 1;
        if (tid < 64) {
            const float zi = pS[tid]       + pS[tid + 256] + zv0;
            const float zf = pS[tid + 64]  + pS[tid + 320] + zv1;
            const float zg = pS[tid + 128] + pS[tid + 384] + zv2;
            const float zo = pS[tid + 192] + pS[tid + 448] + zv3;
            const float si = 1.0f / (1.0f + expf(-zi));
            const float sf = 1.0f / (1.0f + expf(-zf));
            const float so = 1.0f / (1.0f + expf(-zo));
            creg = sf * creg + si * tanhf(zg);
            const float hn = so * tanhf(creg);
            const int e = q * 64 + tid;
            hN[e] = hn;
            lstm_out[(long long)(t * 32 + b) * 512 + d * 256 + e] = hn;
            const unsigned long long tv =
                ((unsigned long long)(unsigned)(s + 1) << 32)
                    | (unsigned long long)__float_as_uint(hn);
            const long long off = (long long)parN * 16384 + hxbase + e;
            *(volatile unsigned long long*)(hxF + off) = tv;  // XCD-L2 fast
            __hip_atomic_store(hxS + off, tv, __ATOMIC_RELAXED,
                               __HIP_MEMORY_SCOPE_AGENT);     // proven slow
        } else if (s < T_LEN - 1) {
            int e = -1;
            if (tid < 256) { if ((tid >> 6) != q) e = tid; }
            else if (tid < 320) { if (q != 0) e = tid - 256; }
            if (e >= 0) {
                const long long off = (long long)parN * 16384 + hxbase + e;
                unsigned long long v;
                int got = 0;
                if (fastOK) {
                    const unsigned long long* sf_p = hxF + off;
                    for (int it = 0; it < 1024; ++it) {
                        asm volatile(
                            "global_load_dwordx2 %0, %1, off sc0\n\t"
                            "s_waitcnt vmcnt(0)"
                            : "=&v"(v) : "v"(sf_p) : "memory");
                        if ((unsigned)(v >> 32) == (unsigned)(s + 1)) {
                            got = 1; break;
                        }
                    }
                    if (!got) fastOK = 0;   // latch: never retry fast
                }
                if (!got) {
                    const unsigned long long* ss_p = hxS + off;
                    do {
                        v = __hip_atomic_load(ss_p, __ATOMIC_RELAXED,
                                              __HIP_MEMORY_SCOPE_AGENT);
                    } while ((unsigned)(v >> 32) != (unsigned)(s + 1));
                }
                hN[e] = __uint_as_float((unsigned)v);
            }
        }
        __syncthreads();
    }
}

// ---------------------------------------------------------------------------
// Kernel 3: feats = lstm_out @ W_out^T + b_out
// ---------------------------------------------------------------------------
__global__ __launch_bounds__(256) void feats_kernel(
    const float* __restrict__ lstm_out, const float* __restrict__ W_out,
    const float* __restrict__ b_out, float* __restrict__ feats)
{
    const int gid = blockIdx.x * 256 + threadIdx.x;
    if (gid >= 8192 * NTAGS) return;
    const int row = gid / NTAGS;
    const int tag = gid - row * NTAGS;
    const float4* x = (const float4*)(lstm_out + (long long)row * 512);
    const float4* w = (const float4*)(W_out + (long long)tag * 512);
    float acc = b_out[tag];
#pragma unroll 4
    for (int k = 0; k < 128; ++k) {
        float4 a = x[k], bw = w[k];
        acc += a.x * bw.x + a.y * bw.y + a.z * bw.z + a.w * bw.w;
    }
    const int t = row >> 5, b = row & 31;
    feats[(long long)b * (T_LEN * NTAGS) + t * NTAGS + tag] = acc;
}

// ---------------------------------------------------------------------------
// Kernel 4: Viterbi per batch. 32 WGs x 64 threads.
// ---------------------------------------------------------------------------
__global__ __launch_bounds__(64) void viterbi_kernel(
    const float* __restrict__ feats, const float* __restrict__ trans,
    float* __restrict__ out)
{
    __shared__ float featS[T_LEN * NTAGS];
    __shared__ float transS[NTAGS * NTAGS];
    __shared__ float fvS[NTAGS];
    __shared__ unsigned char bpS[T_LEN][NTAGS];
    __shared__ float pathS[T_LEN];

    const int b = blockIdx.x;
    const int lane = threadIdx.x;

    {
        const float4* src = (const float4*)(feats + (long long)b * (T_LEN * NTAGS));
        float4* dst = (float4*)featS;
        for (int i = lane; i < (T_LEN * NTAGS) / 4; i += 64) dst[i] = src[i];
        for (int i = lane; i < NTAGS * NTAGS; i += 64) transS[i] = trans[i];
    }
    __syncthreads();

    float fv[NTAGS];
#pragma unroll
    for (int p = 0; p < NTAGS; ++p) fv[p] = (p == 10) ? 0.0f : NEGV;

    for (int t = 0; t < T_LEN; ++t) {
        if (lane < NTAGS) {
            float best = -3.4e38f; int bi = 0;
#pragma unroll
            for (int p = 0; p < NTAGS; ++p) {
                const float v = fv[p] + transS[lane * NTAGS + p];
                if (v > best) { best = v; bi = p; }
            }
            bpS[t][lane] = (unsigned char)bi;
            fvS[lane] = best + featS[t * NTAGS + lane];
        }
        __syncthreads();
#pragma unroll
        for (int p = 0; p < NTAGS; ++p) fv[p] = fvS[p];
        __syncthreads();
    }

    if (lane < NTAGS) fvS[lane] = fv[lane] + transS[11 * NTAGS + lane];
    __syncthreads();
    if (lane == 0) {
        float best = -3.4e38f; int bi = 0;
        for (int p = 0; p < NTAGS; ++p) {
            const float v = fvS[p];
            if (v > best) { best = v; bi = p; }
        }
        out[b] = best;
        int cur = bi;
        pathS[T_LEN - 1] = (float)cur;
        for (int tt = T_LEN - 2; tt >= 0; --tt) {
            cur = bpS[tt + 1][cur];
            pathS[tt] = (float)cur;
        }
    }
    __syncthreads();
    float* po = out + BATCH + (long long)b * T_LEN;
    for (int i = lane; i < T_LEN; i += 64) po[i] = pathS[i];
}

// ---------------------------------------------------------------------------
extern "C" void kernel_launch(void* const* d_in, const int* in_sizes, int n_in,
                              void* d_out, int out_size, void* d_ws, size_t ws_size,
                              hipStream_t stream)
{
    (void)in_sizes; (void)n_in; (void)out_size; (void)ws_size;
    const int*   sentence = (const int*)  d_in[0];
    const float* embed    = (const float*)d_in[1];
    const float* W_ih_f   = (const float*)d_in[2];
    const float* W_hh_f   = (const float*)d_in[3];
    const float* b_f      = (const float*)d_in[4];
    const float* W_ih_b   = (const float*)d_in[5];
    const float* W_hh_b   = (const float*)d_in[6];
    const float* b_b      = (const float*)d_in[7];
    const float* W_out    = (const float*)d_in[8];
    const float* b_out    = (const float*)d_in[9];
    const float* trans    = (const float*)d_in[10];
    const float* h0       = (const float*)d_in[11];
    const float* c0       = (const float*)d_in[12];
    float* out = (float*)d_out;

    char* ws = (char*)d_ws;
    float* zx       = (float*)ws; ws += (long long)8192 * 2048 * 4;   // 64 MB
    float* lstm_out = (float*)ws; ws += (long long)8192 * 512 * 4;    // 16 MB
    float* feats    = (float*)ws; ws += BATCH * T_LEN * NTAGS * 4;    // 384 KB
    float* pack     = (float*)ws; ws += (long long)524288 * 4;        // 2 MB
    unsigned long long* hxS = (unsigned long long*)ws; ws += 2 * 16384 * 8; // 256 KB
    unsigned long long* hxF = (unsigned long long*)ws; ws += 2 * 16384 * 8; // 256 KB
    // hxS/hxF re-poisoned to 0xAA before every launch -> tags invalid.

    pack_whh<<<2048, 256, 0, stream>>>(W_hh_f, W_hh_b, pack);
    gemm_zx<<<1024, 256, 0, stream>>>(sentence, embed, W_ih_f, W_ih_b, b_f, b_b, zx);
    lstm_team<<<256, 512, 0, stream>>>(zx, pack, h0, c0, hxF, hxS, lstm_out);
    feats_kernel<<<384, 256, 0, stream>>>(lstm_out, W_out, b_out, feats);
    viterbi_kernel<<<32, 64, 0, stream>>>(feats, trans, out);
}

// Round 3
// 965.907 us; speedup vs baseline: 1.1070x; 1.1070x over previous
//
#include <hip/hip_runtime.h>
#include <math.h>

// Problem constants
#define T_LEN  256
#define BATCH  32
#define EMBD   256
#define HHD    256           // per-direction hidden
#define NTAGS  12
#define NEGV   (-10000.0f)

typedef unsigned int u32x4 __attribute__((ext_vector_type(4)));

// ---------------------------------------------------------------------------
// Kernel 1: zx = gather(embed)[m,:] @ [W_ih_f | W_ih_b]^T + bias
// M = 8192 rows (m = t*32 + b), N = 2048, K = 256. 128x128x16 tile.
// R3: OUTPUT LAYOUT gate-interleaved: zx[row][d*1024 + e*4 + g]  (g=i,f,g,o)
// so the lstm gate wave reads ONE dwordx4 per step instead of 4 scalars.
// Store side becomes 16 scalar stores per i-iter (stride 16B) — negligible
// in this VALU-bound kernel; L2 write-combines the lines.
// ---------------------------------------------------------------------------
__global__ __launch_bounds__(256) void gemm_zx(
    const int* __restrict__ sentence, const float* __restrict__ embed,
    const float* __restrict__ Wf,  const float* __restrict__ Wb,
    const float* __restrict__ bf,  const float* __restrict__ bb,
    float* __restrict__ zx)
{
    __shared__ float As[16][132];
    __shared__ float Bs[16][132];

    const int tid = threadIdx.x;
    const int tx = tid & 15, ty = tid >> 4;
    const int Mbase = (int)(blockIdx.x >> 4) * 128;
    const int Nbase = (int)(blockIdx.x & 15) * 128;

    const float* Wsrc = (Nbase < 1024) ? Wf : Wb;
    const float* bsrc = (Nbase < 1024) ? bf : bb;
    const int nOff = (Nbase < 1024) ? Nbase : (Nbase - 1024);

    const int m0 = tid >> 2;
    const int m1 = m0 + 64;
    const int kq = (tid & 3) * 4;
    const int mg0 = Mbase + m0, mg1 = Mbase + m1;
    const int tok0 = sentence[(mg0 & 31) * T_LEN + (mg0 >> 5)];
    const int tok1 = sentence[(mg1 & 31) * T_LEN + (mg1 >> 5)];
    const float* arow0 = embed + (long long)tok0 * EMBD;
    const float* arow1 = embed + (long long)tok1 * EMBD;
    const float* brow0 = Wsrc + (long long)(nOff + m0) * EMBD;
    const float* brow1 = Wsrc + (long long)(nOff + m1) * EMBD;

    float acc[8][8];
#pragma unroll
    for (int i = 0; i < 8; ++i)
#pragma unroll
        for (int j = 0; j < 8; ++j) acc[i][j] = 0.0f;

    for (int k0 = 0; k0 < EMBD; k0 += 16) {
        float4 av0 = *(const float4*)(arow0 + k0 + kq);
        float4 av1 = *(const float4*)(arow1 + k0 + kq);
        float4 bv0 = *(const float4*)(brow0 + k0 + kq);
        float4 bv1 = *(const float4*)(brow1 + k0 + kq);
        __syncthreads();
        As[kq+0][m0] = av0.x; As[kq+1][m0] = av0.y; As[kq+2][m0] = av0.z; As[kq+3][m0] = av0.w;
        As[kq+0][m1] = av1.x; As[kq+1][m1] = av1.y; As[kq+2][m1] = av1.z; As[kq+3][m1] = av1.w;
        Bs[kq+0][m0] = bv0.x; Bs[kq+1][m0] = bv0.y; Bs[kq+2][m0] = bv0.z; Bs[kq+3][m0] = bv0.w;
        Bs[kq+0][m1] = bv1.x; Bs[kq+1][m1] = bv1.y; Bs[kq+2][m1] = bv1.z; Bs[kq+3][m1] = bv1.w;
        __syncthreads();
#pragma unroll
        for (int kt = 0; kt < 16; ++kt) {
            float am[8], bn[8];
            *(float4*)&am[0] = *(const float4*)&As[kt][ty * 4];
            *(float4*)&am[4] = *(const float4*)&As[kt][64 + ty * 4];
            *(float4*)&bn[0] = *(const float4*)&Bs[kt][tx * 4];
            *(float4*)&bn[4] = *(const float4*)&Bs[kt][64 + tx * 4];
#pragma unroll
            for (int i = 0; i < 8; ++i)
#pragma unroll
                for (int j = 0; j < 8; ++j) acc[i][j] += am[i] * bn[j];
        }
    }

    float4 bias0 = *(const float4*)(bsrc + nOff + tx * 4);
    float4 bias1 = *(const float4*)(bsrc + nOff + 64 + tx * 4);
    const float bnv[8] = {bias0.x, bias0.y, bias0.z, bias0.w,
                          bias1.x, bias1.y, bias1.z, bias1.w};
    const int N0 = Nbase + tx * 4;            // 64-run, single gate
    const int N1 = N0 + 64;
    const int d0 = N0 >> 10, g0 = (N0 >> 8) & 3, e0 = N0 & 255;
    const int d1 = N1 >> 10, g1 = (N1 >> 8) & 3, e1 = N1 & 255;
#pragma unroll
    for (int i = 0; i < 8; ++i) {
        const int mg = Mbase + ty * 4 + (i & 3) + ((i >= 4) ? 64 : 0);
        float* p0 = zx + (long long)mg * 2048 + d0 * 1024 + e0 * 4 + g0;
        float* p1 = zx + (long long)mg * 2048 + d1 * 1024 + e1 * 4 + g1;
        p0[0]  = acc[i][0] + bnv[0];
        p0[4]  = acc[i][1] + bnv[1];
        p0[8]  = acc[i][2] + bnv[2];
        p0[12] = acc[i][3] + bnv[3];
        p1[0]  = acc[i][4] + bnv[4];
        p1[4]  = acc[i][5] + bnv[5];
        p1[8]  = acc[i][6] + bnv[6];
        p1[12] = acc[i][7] + bnv[7];
    }
}

// ---------------------------------------------------------------------------
// Kernel 1b: pack W_hh into per-(slice,thread) contiguous 512 B chunks:
// offset = (((d*4+q)*2 + half)*256 + j)*128 + k2
//   j = gate-row within WG (g = j>>6, e = q*64 + (j&63)), k = half*128+k2.
// lstm_team WG with slice sl = d*4+q, thread tid reads chunk at tid*128.
// ---------------------------------------------------------------------------
__global__ __launch_bounds__(256) void pack_whh(
    const float* __restrict__ Whf, const float* __restrict__ Whb,
    float* __restrict__ pack)
{
    const int gid = blockIdx.x * 256 + threadIdx.x;   // 0..524287
    const int k2   = gid & 127;
    const int j    = (gid >> 7) & 255;
    const int half = (gid >> 15) & 1;
    const int q    = (gid >> 16) & 3;
    const int d    = (gid >> 18) & 1;
    const float* W = d ? Whb : Whf;
    const int g = j >> 6;
    const int e = q * 64 + (j & 63);
    pack[gid] = W[(g * 256 + e) * 256 + half * 128 + k2];
}

// ---------------------------------------------------------------------------
// Kernel 2: REGISTER-RESIDENT team LSTM.  256 WGs x 512 threads.
// R3: dual-channel exchange kept (R2 proved it ENGAGES: FETCH -17MB), but
// the R2 regression (718 vs 555us) was the sc0 POLL STORM saturating the
// XCD L2 (~25 req/cy/XCD) and delaying zx loads + store visibility. Fixes:
//   (a) 96 pollers/WG (was 240), each polling a 16B dwordx4 sc0 covering
//       TWO tagged slots; s_sleep 1 backoff between failed polls ->
//       ~6 req/cy/XCD.
//   (b) zx loads: one dwordx4/step (new gate-interleaved layout) prefetched
//       ONE FULL STEP ahead -> a whole step of slack; L2 congestion can't
//       put zx on the critical path.
//   (c) fast-timeout bound 256 iters (latch window ~35us, then pure slow).
// Safety unchanged: producer stores BOTH hxF (plain volatile -> XCD L2) and
// hxS (agent-scope atomic -> proven channel). Consumer timeout latches
// fastOK=0 and falls back to the unbounded agent poll -> placement can cost
// perf, never correctness, never a hang (G16).
// blockIdx remap: partners differ only in bits 4:3 -> same bx%8 AND same
// bx/32 -> co-located under round-robin OR chunked dispatch.
// W pinned via empty inline-asm "+v" (R5 lesson: blocks rematerialization).
// ---------------------------------------------------------------------------
__global__ __launch_bounds__(512, 2) void lstm_team(
    const float* __restrict__ zx, const float* __restrict__ pack,
    const float* __restrict__ h0, const float* __restrict__ c0,
    unsigned long long* __restrict__ hxF,   // fast: [2 par][2 d][32 b][256 e]
    unsigned long long* __restrict__ hxS,   // slow: same layout
    float* __restrict__ lstm_out)
{
    __shared__ float hS0[256];
    __shared__ float hS1[256];
    __shared__ float pS[512];

    const int tid = threadIdx.x;
    const int bx  = (int)blockIdx.x;
    const int b  = ((bx >> 5) & 3) * 8 + (bx & 7);
    const int q  = (bx >> 3) & 3;
    const int d  = (bx >> 7) & 1;
    const int sl = d * 4 + q;

    // --- W half-row into registers (one-time, coalesced) ---
    float4 wreg[32];
    {
        const float4* wrow = (const float4*)(pack + ((long long)sl << 16)
                                             + tid * 128);
#pragma unroll
        for (int c = 0; c < 32; ++c) wreg[c] = wrow[c];
    }
    // Forbid rematerialization: values become asm outputs, not loads.
#pragma unroll
    for (int c = 0; c < 32; ++c) {
        asm volatile("" : "+v"(wreg[c].x), "+v"(wreg[c].y),
                          "+v"(wreg[c].z), "+v"(wreg[c].w));
    }

    const int half = tid >> 8;            // k-half this thread dots
    const long long hxbase = (long long)(d * 32 + b) * 256;
    float creg = (tid < 64) ? c0[(d * 32 + b) * 256 + q * 64 + tid] : 0.0f;
    int fastOK = 1;

    // poller assignment: tid 64..159 -> pid 0..95, two slots each
    const int pid = tid - 64;
    int e0p = -1;
    if (pid >= 0 && pid < 96) {
        const int jj = pid >> 5;            // 0..2
        const int pj = pid & 31;            // pair within quarter
        const int qq = jj + (jj >= q);      // skip own quarter
        e0p = qq * 64 + pj * 2;
    }

    if (tid < 256) hS0[tid] = h0[(d * 32 + b) * 256 + tid];
    __syncthreads();

    // zx pipeline: current step's float4 loaded one step ahead
    const float* zbase = zx + (long long)d * 1024 + (q * 64 + (tid & 63)) * 4;
    float4 zv = make_float4(0.f, 0.f, 0.f, 0.f);
    if (tid < 64) {
        const int t0 = d ? (T_LEN - 1) : 0;
        zv = *(const float4*)(zbase + (long long)(t0 * 32 + b) * 2048);
    }

    for (int s = 0; s < T_LEN; ++s) {
        const int t = d ? (T_LEN - 1 - s) : s;

        // prefetch NEXT step's zx (full step of latency slack)
        float4 zn = zv;
        if (tid < 64 && s < T_LEN - 1) {
            const int tn = d ? (T_LEN - 2 - s) : (s + 1);
            zn = *(const float4*)(zbase + (long long)(tn * 32 + b) * 2048);
        }

        const float* h  = (s & 1) ? hS1 : hS0;
        float*       hN = (s & 1) ? hS0 : hS1;
        const float* hh = h + half * 128;   // wave-uniform -> LDS broadcast

        // --- half-dot from registers ---
        float a = 0.0f;
#pragma unroll
        for (int c = 0; c < 32; ++c) {
            const float4 hv = *(const float4*)(hh + c * 4);
            a += wreg[c].x * hv.x + wreg[c].y * hv.y
               + wreg[c].z * hv.z + wreg[c].w * hv.w;
        }
        pS[tid] = a;
        __syncthreads();

        const int parN = (s & 1) ^ 1;
        if (tid < 64) {
            const float zi = pS[tid]       + pS[tid + 256] + zv.x;
            const float zf = pS[tid + 64]  + pS[tid + 320] + zv.y;
            const float zg = pS[tid + 128] + pS[tid + 384] + zv.z;
            const float zo = pS[tid + 192] + pS[tid + 448] + zv.w;
            const float si = 1.0f / (1.0f + expf(-zi));
            const float sf = 1.0f / (1.0f + expf(-zf));
            const float so = 1.0f / (1.0f + expf(-zo));
            creg = sf * creg + si * tanhf(zg);
            const float hn = so * tanhf(creg);
            const int e = q * 64 + tid;
            hN[e] = hn;
            lstm_out[(long long)(t * 32 + b) * 512 + d * 256 + e] = hn;
            const unsigned long long tv =
                ((unsigned long long)(unsigned)(s + 1) << 32)
                    | (unsigned long long)__float_as_uint(hn);
            const long long off = (long long)parN * 16384 + hxbase + e;
            *(volatile unsigned long long*)(hxF + off) = tv;  // XCD-L2 fast
            __hip_atomic_store(hxS + off, tv, __ATOMIC_RELAXED,
                               __HIP_MEMORY_SCOPE_AGENT);     // proven slow
        } else if (e0p >= 0 && s < T_LEN - 1) {
            const long long off = (long long)parN * 16384 + hxbase + e0p;
            const unsigned tag = (unsigned)(s + 1);
            u32x4 v;
            int got = 0;
            if (fastOK) {
                const unsigned long long* fp = hxF + off;   // 16B aligned
                for (int it = 0; it < 256; ++it) {
                    asm volatile(
                        "global_load_dwordx4 %0, %1, off sc0\n\t"
                        "s_waitcnt vmcnt(0)"
                        : "=&v"(v) : "v"(fp) : "memory");
                    if (v.y == tag && v.w == tag) { got = 1; break; }
                    asm volatile("s_sleep 1");
                }
                if (!got) fastOK = 0;   // latch: never retry fast
            }
            if (got) {
                hN[e0p]     = __uint_as_float(v.x);
                hN[e0p + 1] = __uint_as_float(v.z);
            } else {
                unsigned long long v0, v1;
                const unsigned long long* s0 = hxS + off;
                do { v0 = __hip_atomic_load(s0, __ATOMIC_RELAXED,
                                            __HIP_MEMORY_SCOPE_AGENT);
                } while ((unsigned)(v0 >> 32) != tag);
                do { v1 = __hip_atomic_load(s0 + 1, __ATOMIC_RELAXED,
                                            __HIP_MEMORY_SCOPE_AGENT);
                } while ((unsigned)(v1 >> 32) != tag);
                hN[e0p]     = __uint_as_float((unsigned)v0);
                hN[e0p + 1] = __uint_as_float((unsigned)v1);
            }
        }
        zv = zn;
        __syncthreads();
    }
}

// ---------------------------------------------------------------------------
// Kernel 3: feats = lstm_out @ W_out^T + b_out
// ---------------------------------------------------------------------------
__global__ __launch_bounds__(256) void feats_kernel(
    const float* __restrict__ lstm_out, const float* __restrict__ W_out,
    const float* __restrict__ b_out, float* __restrict__ feats)
{
    const int gid = blockIdx.x * 256 + threadIdx.x;
    if (gid >= 8192 * NTAGS) return;
    const int row = gid / NTAGS;
    const int tag = gid - row * NTAGS;
    const float4* x = (const float4*)(lstm_out + (long long)row * 512);
    const float4* w = (const float4*)(W_out + (long long)tag * 512);
    float acc = b_out[tag];
#pragma unroll 4
    for (int k = 0; k < 128; ++k) {
        float4 a = x[k], bw = w[k];
        acc += a.x * bw.x + a.y * bw.y + a.z * bw.z + a.w * bw.w;
    }
    const int t = row >> 5, b = row & 31;
    feats[(long long)b * (T_LEN * NTAGS) + t * NTAGS + tag] = acc;
}

// ---------------------------------------------------------------------------
// Kernel 4: Viterbi per batch. 32 WGs x 64 threads.
// ---------------------------------------------------------------------------
__global__ __launch_bounds__(64) void viterbi_kernel(
    const float* __restrict__ feats, const float* __restrict__ trans,
    float* __restrict__ out)
{
    __shared__ float featS[T_LEN * NTAGS];
    __shared__ float transS[NTAGS * NTAGS];
    __shared__ float fvS[NTAGS];
    __shared__ unsigned char bpS[T_LEN][NTAGS];
    __shared__ float pathS[T_LEN];

    const int b = blockIdx.x;
    const int lane = threadIdx.x;

    {
        const float4* src = (const float4*)(feats + (long long)b * (T_LEN * NTAGS));
        float4* dst = (float4*)featS;
        for (int i = lane; i < (T_LEN * NTAGS) / 4; i += 64) dst[i] = src[i];
        for (int i = lane; i < NTAGS * NTAGS; i += 64) transS[i] = trans[i];
    }
    __syncthreads();

    float fv[NTAGS];
#pragma unroll
    for (int p = 0; p < NTAGS; ++p) fv[p] = (p == 10) ? 0.0f : NEGV;

    for (int t = 0; t < T_LEN; ++t) {
        if (lane < NTAGS) {
            float best = -3.4e38f; int bi = 0;
#pragma unroll
            for (int p = 0; p < NTAGS; ++p) {
                const float v = fv[p] + transS[lane * NTAGS + p];
                if (v > best) { best = v; bi = p; }
            }
            bpS[t][lane] = (unsigned char)bi;
            fvS[lane] = best + featS[t * NTAGS + lane];
        }
        __syncthreads();
#pragma unroll
        for (int p = 0; p < NTAGS; ++p) fv[p] = fvS[p];
        __syncthreads();
    }

    if (lane < NTAGS) fvS[lane] = fv[lane] + transS[11 * NTAGS + lane];
    __syncthreads();
    if (lane == 0) {
        float best = -3.4e38f; int bi = 0;
        for (int p = 0; p < NTAGS; ++p) {
            const float v = fvS[p];
            if (v > best) { best = v; bi = p; }
        }
        out[b] = best;
        int cur = bi;
        pathS[T_LEN - 1] = (float)cur;
        for (int tt = T_LEN - 2; tt >= 0; --tt) {
            cur = bpS[tt + 1][cur];
            pathS[tt] = (float)cur;
        }
    }
    __syncthreads();
    float* po = out + BATCH + (long long)b * T_LEN;
    for (int i = lane; i < T_LEN; i += 64) po[i] = pathS[i];
}

// ---------------------------------------------------------------------------
extern "C" void kernel_launch(void* const* d_in, const int* in_sizes, int n_in,
                              void* d_out, int out_size, void* d_ws, size_t ws_size,
                              hipStream_t stream)
{
    (void)in_sizes; (void)n_in; (void)out_size; (void)ws_size;
    const int*   sentence = (const int*)  d_in[0];
    const float* embed    = (const float*)d_in[1];
    const float* W_ih_f   = (const float*)d_in[2];
    const float* W_hh_f   = (const float*)d_in[3];
    const float* b_f      = (const float*)d_in[4];
    const float* W_ih_b   = (const float*)d_in[5];
    const float* W_hh_b   = (const float*)d_in[6];
    const float* b_b      = (const float*)d_in[7];
    const float* W_out    = (const float*)d_in[8];
    const float* b_out    = (const float*)d_in[9];
    const float* trans    = (const float*)d_in[10];
    const float* h0       = (const float*)d_in[11];
    const float* c0       = (const float*)d_in[12];
    float* out = (float*)d_out;

    char* ws = (char*)d_ws;
    float* zx       = (float*)ws; ws += (long long)8192 * 2048 * 4;   // 64 MB
    float* lstm_out = (float*)ws; ws += (long long)8192 * 512 * 4;    // 16 MB
    float* feats    = (float*)ws; ws += BATCH * T_LEN * NTAGS * 4;    // 384 KB
    float* pack     = (float*)ws; ws += (long long)524288 * 4;        // 2 MB
    unsigned long long* hxS = (unsigned long long*)ws; ws += 2 * 16384 * 8; // 256 KB
    unsigned long long* hxF = (unsigned long long*)ws; ws += 2 * 16384 * 8; // 256 KB
    // hxS/hxF re-poisoned to 0xAA before every launch -> tags invalid.

    pack_whh<<<2048, 256, 0, stream>>>(W_hh_f, W_hh_b, pack);
    gemm_zx<<<1024, 256, 0, stream>>>(sentence, embed, W_ih_f, W_ih_b, b_f, b_b, zx);
    lstm_team<<<256, 512, 0, stream>>>(zx, pack, h0, c0, hxF, hxS, lstm_out);
    feats_kernel<<<384, 256, 0, stream>>>(lstm_out, W_out, b_out, feats);
    viterbi_kernel<<<32, 64, 0, stream>>>(feats, trans, out);
}